// Round 1
// baseline (128.500 us; speedup 1.0000x reference)
//
#include <hip/hip_runtime.h>

#define Hn 28
#define Wn 28
#define NI 128      // B*I = 8*16
#define PQ 784      // 28*28

__device__ __forceinline__ float gelu_exact(float x) {
    return 0.5f * x * (1.0f + erff(x * 0.70710678118654752440f));
}

// vT[s][p][ni] = v[ni][p][s]  (so the fused kernel stages coalesced float4)
__global__ __launch_bounds__(256) void vtrans_kernel(const float* __restrict__ v,
                                                     float* __restrict__ vT) {
    const int ni = blockIdx.x;      // 0..127
    const int t = threadIdx.x;
    for (int e = t; e < PQ; e += 256) {
        const int p = e / Wn;
        const int s = e - p * Wn;
        vT[s * (Hn * NI) + p * NI + ni] = v[ni * PQ + e];
    }
}

// One block per (r,s). Computes Hsum over q in LDS, then T = V*Hsum, then W2 contraction.
__global__ __launch_bounds__(256, 2) void fused_kernel(
    const float* __restrict__ vT, const float* __restrict__ W1,
    const float* __restrict__ b1, const float* __restrict__ W2,
    const float* __restrict__ b2, const float* __restrict__ bias,
    float* __restrict__ out)
{
    __shared__ float sH[Hn * 64];      // [p][c]          7168 B
    __shared__ float sVT[Hn * NI];     // [p][ni]        14336 B
    __shared__ float sTt[64 * 132];    // [c][ni] pad132 33792 B
    __shared__ float sVsum[NI];        //                  512 B
    __shared__ float sCpart[NI];       //                  512 B

    const int t = threadIdx.x;
    const int rs = blockIdx.x;
    const int r = rs / Wn;
    const int s = rs - r * Wn;

    // A. stage v[:,:, :, s] as [p][ni] — coalesced float4 from vT
    {
        const float4* src = (const float4*)(vT + s * (Hn * NI));
        float4* dst = (float4*)sVT;
        #pragma unroll
        for (int k = 0; k < 4; ++k) {
            const int j = t + 256 * k;
            if (j < (Hn * NI) / 4) dst[j] = src[j];
        }
    }

    // B. sH[p][c] = sum_q gelu(xp*W1[0,c] + xq*W1[1,c] + xr*W1[2,c] + xs*W1[3,c] + b1[c])
    {
        const int c = t & 63;
        const int pg = t >> 6;         // 0..3, each does 7 p's
        const float w10 = W1[c];
        const float w11 = W1[64 + c];
        const float w12 = W1[128 + c];
        const float w13 = W1[192 + c];
        const float inv = 1.0f / 28.0f;
        const float base_rs = ((r + 0.5f) * inv) * w12 + ((s + 0.5f) * inv) * w13 + b1[c];
        #pragma unroll
        for (int pi = 0; pi < 7; ++pi) {
            const int p = pg * 7 + pi;
            const float base = base_rs + ((p + 0.5f) * inv) * w10;
            float acc = 0.0f;
            #pragma unroll
            for (int q = 0; q < 28; ++q) {
                acc += gelu_exact(base + ((q + 0.5f) * inv) * w11);
            }
            sH[p * 64 + c] = acc;
        }
    }
    __syncthreads();

    // C. column sums of the v slice (for the b2 term)
    if (t < NI) {
        float vs = 0.0f;
        #pragma unroll
        for (int p = 0; p < Hn; ++p) vs += sVT[p * NI + t];
        sVsum[t] = vs;
    }

    // D. T[ni][c] = sum_p sVT[p][ni] * sH[p][c], register tile 8 ni x 4 c per thread
    {
        const int cg = t & 15;        // c = cg*4 .. cg*4+3
        const int nig = t >> 4;       // ni = nig*8 .. nig*8+7
        float acc[8][4];
        #pragma unroll
        for (int k = 0; k < 8; ++k)
            #pragma unroll
            for (int j = 0; j < 4; ++j) acc[k][j] = 0.0f;
        for (int p = 0; p < Hn; ++p) {
            const float4 h4 = *(const float4*)&sH[p * 64 + cg * 4];
            const float4 va = *(const float4*)&sVT[p * NI + nig * 8];
            const float4 vb = *(const float4*)&sVT[p * NI + nig * 8 + 4];
            const float hh[4] = {h4.x, h4.y, h4.z, h4.w};
            const float vv[8] = {va.x, va.y, va.z, va.w, vb.x, vb.y, vb.z, vb.w};
            #pragma unroll
            for (int k = 0; k < 8; ++k)
                #pragma unroll
                for (int j = 0; j < 4; ++j)
                    acc[k][j] += vv[k] * hh[j];
        }
        #pragma unroll
        for (int j = 0; j < 4; ++j) {
            const int c = cg * 4 + j;
            const float4 t0 = make_float4(acc[0][j], acc[1][j], acc[2][j], acc[3][j]);
            const float4 t1 = make_float4(acc[4][j], acc[5][j], acc[6][j], acc[7][j]);
            *(float4*)&sTt[c * 132 + nig * 8]     = t0;
            *(float4*)&sTt[c * 132 + nig * 8 + 4] = t1;
        }
    }
    __syncthreads();

    // E. out[n][o] = quad*(sum_{c,i} T[n*16+i][c]*W2[c][o*16+i] + 28*sum_i b2[o*16+i]*Vsum[n,i]) + bias[o]
    float acc2 = 0.0f;
    const int half = t >> 7;          // split c-range across 2 threads per output
    const int no = t & 127;
    const int n = no >> 4;
    const int o = no & 15;
    {
        const int c0 = half * 32;
        for (int cc = 0; cc < 32; ++cc) {
            const int c = c0 + cc;
            const float* trow = &sTt[c * 132 + n * 16];
            const float* wrow = &W2[c * 256 + o * 16];
            const float4 tv0 = *(const float4*)&trow[0];
            const float4 tv1 = *(const float4*)&trow[4];
            const float4 tv2 = *(const float4*)&trow[8];
            const float4 tv3 = *(const float4*)&trow[12];
            const float4 wv0 = *(const float4*)&wrow[0];
            const float4 wv1 = *(const float4*)&wrow[4];
            const float4 wv2 = *(const float4*)&wrow[8];
            const float4 wv3 = *(const float4*)&wrow[12];
            acc2 += tv0.x*wv0.x + tv0.y*wv0.y + tv0.z*wv0.z + tv0.w*wv0.w
                  + tv1.x*wv1.x + tv1.y*wv1.y + tv1.z*wv1.z + tv1.w*wv1.w
                  + tv2.x*wv2.x + tv2.y*wv2.y + tv2.z*wv2.z + tv2.w*wv2.w
                  + tv3.x*wv3.x + tv3.y*wv3.y + tv3.z*wv3.z + tv3.w*wv3.w;
        }
    }
    if (half == 1) sCpart[no] = acc2;
    __syncthreads();
    if (half == 0) {
        const float total = acc2 + sCpart[no];
        float bsum = 0.0f;
        #pragma unroll
        for (int i4 = 0; i4 < 4; ++i4) {
            const float4 bv = *(const float4*)&b2[o * 16 + i4 * 4];
            bsum += bv.x * sVsum[n * 16 + i4 * 4 + 0]
                  + bv.y * sVsum[n * 16 + i4 * 4 + 1]
                  + bv.z * sVsum[n * 16 + i4 * 4 + 2]
                  + bv.w * sVsum[n * 16 + i4 * 4 + 3];
        }
        const float quad = 1.0f / 784.0f;
        out[(n * 16 + o) * PQ + r * Wn + s] = quad * (total + 28.0f * bsum) + bias[o];
    }
}

extern "C" void kernel_launch(void* const* d_in, const int* in_sizes, int n_in,
                              void* d_out, int out_size, void* d_ws, size_t ws_size,
                              hipStream_t stream) {
    const float* v    = (const float*)d_in[0];  // (8,16,28,28)
    const float* W1   = (const float*)d_in[1];  // (4,64)
    const float* b1   = (const float*)d_in[2];  // (64,)
    const float* W2   = (const float*)d_in[3];  // (64,256)
    const float* b2   = (const float*)d_in[4];  // (256,)
    const float* bias = (const float*)d_in[5];  // (16,1,1)
    float* out = (float*)d_out;                 // (8,16,28,28) fp32
    float* vT  = (float*)d_ws;                  // 28*28*128 floats = 401408 B

    vtrans_kernel<<<NI, 256, 0, stream>>>(v, vT);
    fused_kernel<<<PQ, 256, 0, stream>>>(vT, W1, b1, W2, b2, bias, out);
}